// Round 1
// baseline (590.313 us; speedup 1.0000x reference)
//
#include <hip/hip_runtime.h>
#include <math.h>

#define NUM_FREQS 10
#define DK 5
#define NCLUST 64
#define EDIM 60           // 3 * 2 * NUM_FREQS
#define NROWS 192         // NCLUST * 3
#define TRADEOFF 1.0f

// posenc layout: enc[l*6 + s*3 + d], s=0 -> sin, s=1 -> cos
__device__ __forceinline__ void posenc3(float x0, float x1, float x2, float* enc) {
#pragma unroll
    for (int l = 0; l < NUM_FREQS; ++l) {
        float f = (float)(1u << l);
        float s0, c0, s1, c1, s2, c2;
        sincosf(x0 * f, &s0, &c0);
        sincosf(x1 * f, &s1, &c1);
        sincosf(x2 * f, &s2, &c2);
        enc[l*6 + 0] = s0; enc[l*6 + 1] = s1; enc[l*6 + 2] = s2;
        enc[l*6 + 3] = c0; enc[l*6 + 4] = c1; enc[l*6 + 5] = c2;
    }
}

// K[c][k] = (posenc(centroid_c) . Wk[k]) / sqrt(DK)
__global__ void compute_K_kernel(const float* __restrict__ centroids,
                                 const float* __restrict__ Wk,
                                 float* __restrict__ Kout) {
    int c = threadIdx.x;
    if (c >= NCLUST) return;
    float enc[EDIM];
    posenc3(centroids[c*3 + 0], centroids[c*3 + 1], centroids[c*3 + 2], enc);
    const float inv_sqrt_dk = 0.44721359549995794f;  // 1/sqrt(5)
#pragma unroll
    for (int k = 0; k < DK; ++k) {
        float acc = 0.f;
#pragma unroll
        for (int e = 0; e < EDIM; ++e) acc = fmaf(enc[e], Wk[k*EDIM + e], acc);
        Kout[c*DK + k] = acc * inv_sqrt_dk;
    }
}

__global__ __launch_bounds__(256) void fused_attn_kernel(
        const float* __restrict__ X,
        const int*   __restrict__ cluster_ids,
        const float* __restrict__ lm,      // [192, 60]
        const float* __restrict__ Wq,      // [5, 60]
        const float* __restrict__ Wv,      // [3, 3]
        const float* __restrict__ Kbuf,    // [64, 5], pre-scaled by 1/sqrt(dk)
        float* __restrict__ out,           // [3 * N * 3]
        int N) {
    __shared__ float s_lm[NROWS * EDIM];       // 46080 B
    __shared__ float s_wq[DK * EDIM];
    __shared__ float s_k[NCLUST * DK];
    __shared__ float s_wv[9];

    const int tid = threadIdx.x;
    for (int i = tid; i < NROWS * EDIM; i += 256) s_lm[i] = lm[i];
    for (int i = tid; i < DK * EDIM; i += 256)    s_wq[i] = Wq[i];
    for (int i = tid; i < NCLUST * DK; i += 256)  s_k[i]  = Kbuf[i];
    if (tid < 9) s_wv[tid] = Wv[tid];
    __syncthreads();

    const int n = blockIdx.x * 256 + tid;
    if (n >= N) return;

    float enc[EDIM];
    posenc3(X[n*3 + 0], X[n*3 + 1], X[n*3 + 2], enc);

    // Q projection: q[k] = enc . Wq[k]
    float q[DK];
#pragma unroll
    for (int k = 0; k < DK; ++k) {
        float acc = 0.f;
#pragma unroll
        for (int e = 0; e < EDIM; ++e) acc = fmaf(enc[e], s_wq[k*EDIM + e], acc);
        q[k] = acc;
    }

    const float wv00 = s_wv[0], wv01 = s_wv[1], wv02 = s_wv[2];
    const float wv10 = s_wv[3], wv11 = s_wv[4], wv12 = s_wv[5];
    const float wv20 = s_wv[6], wv21 = s_wv[7], wv22 = s_wv[8];

    const int cid = cluster_ids[n];
    float m = -INFINITY, ssum = 0.f;
    float a0 = 0.f, a1 = 0.f, a2 = 0.f;
    float km0 = 0.f, km1 = 0.f, km2 = 0.f;

    for (int c = 0; c < NCLUST; ++c) {
        const float* row = &s_lm[c * (3 * EDIM)];   // rows 3c, 3c+1, 3c+2
        float r0 = 0.f, r1 = 0.f, r2 = 0.f;
#pragma unroll
        for (int e = 0; e < EDIM; ++e) {
            const float a = enc[e];
            r0 = fmaf(a, row[e], r0);
            r1 = fmaf(a, row[EDIM + e], r1);
            r2 = fmaf(a, row[2*EDIM + e], r2);
        }
        const float* kr = &s_k[c * DK];
        const float sc = q[0]*kr[0] + q[1]*kr[1] + q[2]*kr[2] + q[3]*kr[3] + q[4]*kr[4];

        // V = rgb @ Wv^T  (V[d] = sum_j rgb[j] * Wv[d][j])
        const float v0 = wv00*r0 + wv01*r1 + wv02*r2;
        const float v1 = wv10*r0 + wv11*r1 + wv12*r2;
        const float v2 = wv20*r0 + wv21*r1 + wv22*r2;

        // online softmax update
        const float nm = fmaxf(m, sc);
        const float scale = __expf(m - nm);   // first iter: exp(-inf) = 0
        const float p = __expf(sc - nm);
        ssum = ssum * scale + p;
        a0 = fmaf(p, v0, a0 * scale);
        a1 = fmaf(p, v1, a1 * scale);
        a2 = fmaf(p, v2, a2 * scale);
        m = nm;

        if (c == cid) { km0 = r0; km1 = r1; km2 = r2; }
    }

    const float inv = 1.0f / ssum;
    const float at0 = a0 * inv, at1 = a1 * inv, at2 = a2 * inv;

    const float o0 = km0 * TRADEOFF + at0 * (1.0f - TRADEOFF);
    const float o1 = km1 * TRADEOFF + at1 * (1.0f - TRADEOFF);
    const float o2 = km2 * TRADEOFF + at2 * (1.0f - TRADEOFF);

    // outputs concatenated: out [N,3], kmeans_rgb [N,3], attention_rgb [N,3]
    float* o_out = out;
    float* o_km  = out + (size_t)N * 3;
    float* o_at  = out + (size_t)N * 6;
    o_out[n*3 + 0] = o0;  o_out[n*3 + 1] = o1;  o_out[n*3 + 2] = o2;
    o_km[n*3 + 0]  = km0; o_km[n*3 + 1]  = km1; o_km[n*3 + 2]  = km2;
    o_at[n*3 + 0]  = at0; o_at[n*3 + 1]  = at1; o_at[n*3 + 2]  = at2;
}

extern "C" void kernel_launch(void* const* d_in, const int* in_sizes, int n_in,
                              void* d_out, int out_size, void* d_ws, size_t ws_size,
                              hipStream_t stream) {
    const float* X         = (const float*)d_in[0];
    const int*   cids      = (const int*)  d_in[1];
    const float* lm        = (const float*)d_in[2];
    const float* Wq        = (const float*)d_in[3];
    const float* Wk        = (const float*)d_in[4];
    const float* Wv        = (const float*)d_in[5];
    const float* centroids = (const float*)d_in[6];
    float* out = (float*)d_out;
    const int N = in_sizes[0] / 3;

    float* Kbuf = (float*)d_ws;  // 64*5 floats

    compute_K_kernel<<<1, 64, 0, stream>>>(centroids, Wk, Kbuf);
    const int blocks = (N + 255) / 256;
    fused_attn_kernel<<<blocks, 256, 0, stream>>>(X, cids, lm, Wq, Wv, Kbuf, out, N);
}

// Round 3
// 186.664 us; speedup vs baseline: 3.1624x; 3.1624x over previous
//
#include <hip/hip_runtime.h>
#include <math.h>

#define NUM_FREQS 10
#define EDIM 60            // 3 * 2 * NUM_FREQS
#define KPAD 64
#define NCLUST 64
#define TRADEOFF 1.0f

typedef __attribute__((ext_vector_type(8))) short bf16x8;
typedef __attribute__((ext_vector_type(4))) float f32x4;

__device__ __forceinline__ unsigned short f2bf(float f) {
    unsigned u = __builtin_bit_cast(unsigned, f);
    u += 0x7FFFu + ((u >> 16) & 1u);          // round-to-nearest-even
    return (unsigned short)(u >> 16);
}

// NeRF posenc, layout enc[l*6 + s*3 + d] (s=0 sin, s=1 cos).
// Exact: sincosf per frequency (used in tiny precompute kernel).
__device__ void posenc3_exact(float x0, float x1, float x2, float* enc) {
    float xs[3] = {x0, x1, x2};
#pragma unroll
    for (int d = 0; d < 3; ++d) {
#pragma unroll
        for (int l = 0; l < NUM_FREQS; ++l) {
            float s, c;
            sincosf(xs[d] * (float)(1u << l), &s, &c);
            enc[l*6 + d] = s; enc[l*6 + 3 + d] = c;
        }
    }
}

// Fast: one sincosf + 9 angle-doublings per dim (freqs are 2^l).
__device__ __forceinline__ void posenc3_fast(float x0, float x1, float x2, float* enc) {
    float xs[3] = {x0, x1, x2};
#pragma unroll
    for (int d = 0; d < 3; ++d) {
        float s, c;
        sincosf(xs[d], &s, &c);
        enc[0*6 + d] = s; enc[0*6 + 3 + d] = c;
#pragma unroll
        for (int l = 1; l < NUM_FREQS; ++l) {
            float s2 = 2.0f * s * c;
            float c2 = 1.0f - 2.0f * s * s;   // cos(2x)
            s = s2; c = c2;
            enc[l*6 + d] = s; enc[l*6 + 3 + d] = c;
        }
    }
}

// Build stationary W [256 rows][64 K] bf16 in d_ws.
// Row r = 64*w + i:
//   i <  48: rgb row: cluster c = 16w + i/3, channel i%3  ->  lm[(c*3+ch)]
//   i >= 48: score row of cluster c = 16w + (i-48):
//            Wscore_c[k] = sum_j Wq[j][k] * (posenc(centroid_c) . Wk[j]) / sqrt(5)
__global__ void precompute_W(const float* __restrict__ lm,
                             const float* __restrict__ Wq,
                             const float* __restrict__ Wk,
                             const float* __restrict__ centroids,
                             unsigned short* __restrict__ Wbuf) {
    const int r = threadIdx.x;            // 0..255
    const int w = r >> 6;
    const int i = r & 63;
    float row[KPAD];
#pragma unroll
    for (int k = 0; k < KPAD; ++k) row[k] = 0.0f;

    if (i < 48) {
        const int c  = w * 16 + i / 3;
        const int ch = i - (i / 3) * 3;
        const float* src = lm + (c * 3 + ch) * EDIM;
        for (int k = 0; k < EDIM; ++k) row[k] = src[k];
    } else {
        const int c = w * 16 + (i - 48);
        float enc[EDIM];
        posenc3_exact(centroids[c*3+0], centroids[c*3+1], centroids[c*3+2], enc);
        const float inv_sqrt_dk = 0.4472135954999579f;
        float kq[5];
        for (int j = 0; j < 5; ++j) {
            float a = 0.0f;
            for (int k = 0; k < EDIM; ++k) a = fmaf(enc[k], Wk[j*EDIM + k], a);
            kq[j] = a * inv_sqrt_dk;
        }
        for (int k = 0; k < EDIM; ++k) {
            float a = 0.0f;
            for (int j = 0; j < 5; ++j) a = fmaf(Wq[j*EDIM + k], kq[j], a);
            row[k] = a;
        }
    }
    for (int k = 0; k < KPAD; ++k) Wbuf[r*KPAD + k] = f2bf(row[k]);
}

// Fused kernel: 256 threads = 4 waves, 256 points per block.
// Wave w holds A-frags for W rows [64w, 64w+64) in registers.
// Per 16-point subtile: MFMA -> C[256 rows][16 pts] in LDS -> combine
// (softmax over 64 score rows + Wv-weighted rgb sum + kmeans pick).
__global__ __launch_bounds__(256) void fused_kernel(
        const float* __restrict__ X,
        const int*   __restrict__ cluster_ids,
        const unsigned short* __restrict__ Wbuf,
        const float* __restrict__ Wv,
        float* __restrict__ out,
        int N) {
    __shared__ unsigned short sA[256 * KPAD];   // enc tile, bf16, XOR-swizzled (32 KB)
    __shared__ float sC[256 * 17];              // C tile, row-padded to 17 (17 KB)

    const int tid  = threadIdx.x;
    const int lane = tid & 63;
    const int wv   = tid >> 6;       // wave id 0..3
    const int g    = lane >> 4;      // k-group 0..3
    const int l15  = lane & 15;

    // --- stationary A-fragments: A[m][k], m = lane&15, k = g*8 + j (+32*kf)
    bf16x8 afr[4][2];
    {
        const bf16x8* W8 = (const bf16x8*)Wbuf;   // granule = 8 shorts
#pragma unroll
        for (int t = 0; t < 4; ++t)
#pragma unroll
            for (int kf = 0; kf < 2; ++kf)
                afr[t][kf] = W8[(wv*64 + t*16 + l15) * 8 + kf*4 + g];
    }

    // --- posenc phase: each thread encodes its own point into LDS (bf16, swizzled)
    const int base = blockIdx.x * 256;
    {
        int n = base + tid; if (n >= N) n = N - 1;
        float enc[KPAD];
        posenc3_fast(X[n*3+0], X[n*3+1], X[n*3+2], enc);
        enc[60] = 0.f; enc[61] = 0.f; enc[62] = 0.f; enc[63] = 0.f;
#pragma unroll
        for (int u = 0; u < 8; ++u) {
            const int slot = u ^ (tid & 7);       // 16B-slot XOR swizzle
            bf16x8 v;
#pragma unroll
            for (int j = 0; j < 8; ++j) v[j] = (short)f2bf(enc[u*8 + j]);
            *(bf16x8*)&sA[tid*KPAD + slot*8] = v;
        }
    }

    const float wv00 = Wv[0], wv01 = Wv[1], wv02 = Wv[2];
    const float wv10 = Wv[3], wv11 = Wv[4], wv12 = Wv[5];
    const float wv20 = Wv[6], wv21 = Wv[7], wv22 = Wv[8];

    const int p_local = tid >> 4;    // point within subtile (combine phase)
    const int tau     = tid & 15;    // 16 helper threads per point
    const int w2      = tau >> 2;    // which wave-slice's clusters this helper covers
    const int cc0     = 4 * (tau & 3);

    __syncthreads();

    float* o_out = out;
    float* o_km  = out + (size_t)N * 3;
    float* o_at  = out + (size_t)N * 6;

    for (int s = 0; s < 16; ++s) {
        // --- B-fragments from enc LDS: B[k][n], n = lane&15 (point), k = g*8+j (+32*kf)
        bf16x8 bfr[2];
#pragma unroll
        for (int kf = 0; kf < 2; ++kf) {
            const int prow = s*16 + l15;
            const int slot = (kf*4 + g) ^ (prow & 7);
            bfr[kf] = *(const bf16x8*)&sA[prow*KPAD + slot*8];
        }
        // --- MFMA: 4 m-subtiles x K=64
        f32x4 acc[4];
#pragma unroll
        for (int t = 0; t < 4; ++t) {
            acc[t] = (f32x4){0.f, 0.f, 0.f, 0.f};
#pragma unroll
            for (int kf = 0; kf < 2; ++kf)
                acc[t] = __builtin_amdgcn_mfma_f32_16x16x32_bf16(afr[t][kf], bfr[kf], acc[t], 0, 0, 0);
        }
        // --- spill C to LDS: D[m][n]: n = lane&15, m = g*4 + reg
#pragma unroll
        for (int t = 0; t < 4; ++t)
#pragma unroll
            for (int rg = 0; rg < 4; ++rg)
                sC[(wv*64 + t*16 + g*4 + rg) * 17 + l15] = acc[t][rg];

        __syncthreads();

        // --- combine: 16 threads per point, 4 clusters each
        {
            const int n = base + s*16 + p_local;
            const int cidn = cluster_ids[n < N ? n : (N - 1)];

            float sc[4], e[4];
#pragma unroll
            for (int j = 0; j < 4; ++j)
                sc[j] = sC[(w2*64 + 48 + cc0 + j) * 17 + p_local];

            float m = fmaxf(fmaxf(sc[0], sc[1]), fmaxf(sc[2], sc[3]));
#pragma unroll
            for (int msk = 1; msk < 16; msk <<= 1)
                m = fmaxf(m, __shfl_xor(m, msk));

            float S = 0.f;
#pragma unroll
            for (int j = 0; j < 4; ++j) { e[j] = __expf(sc[j] - m); S += e[j]; }
#pragma unroll
            for (int msk = 1; msk < 16; msk <<= 1)
                S += __shfl_xor(S, msk);

            float at0 = 0.f, at1 = 0.f, at2 = 0.f;
            float km0 = 0.f, km1 = 0.f, km2 = 0.f;
#pragma unroll
            for (int j = 0; j < 4; ++j) {
                const int rrow = w2*64 + 3*(cc0 + j);
                const float r0 = sC[(rrow    ) * 17 + p_local];
                const float r1 = sC[(rrow + 1) * 17 + p_local];
                const float r2 = sC[(rrow + 2) * 17 + p_local];
                const float v0 = wv00*r0 + wv01*r1 + wv02*r2;
                const float v1 = wv10*r0 + wv11*r1 + wv12*r2;
                const float v2 = wv20*r0 + wv21*r1 + wv22*r2;
                at0 = fmaf(e[j], v0, at0);
                at1 = fmaf(e[j], v1, at1);
                at2 = fmaf(e[j], v2, at2);
                if (cidn == w2*16 + cc0 + j) { km0 = r0; km1 = r1; km2 = r2; }
            }
#pragma unroll
            for (int msk = 1; msk < 16; msk <<= 1) {
                at0 += __shfl_xor(at0, msk);
                at1 += __shfl_xor(at1, msk);
                at2 += __shfl_xor(at2, msk);
                km0 += __shfl_xor(km0, msk);
                km1 += __shfl_xor(km1, msk);
                km2 += __shfl_xor(km2, msk);
            }
            if (tau == 0 && n < N) {
                const float inv = 1.0f / S;
                const float a0 = at0 * inv, a1 = at1 * inv, a2 = at2 * inv;
                const float o0 = km0 * TRADEOFF + a0 * (1.0f - TRADEOFF);
                const float o1 = km1 * TRADEOFF + a1 * (1.0f - TRADEOFF);
                const float o2 = km2 * TRADEOFF + a2 * (1.0f - TRADEOFF);
                o_out[n*3+0] = o0;  o_out[n*3+1] = o1;  o_out[n*3+2] = o2;
                o_km[n*3+0]  = km0; o_km[n*3+1]  = km1; o_km[n*3+2]  = km2;
                o_at[n*3+0]  = a0;  o_at[n*3+1]  = a1;  o_at[n*3+2]  = a2;
            }
        }
        __syncthreads();
    }
}

extern "C" void kernel_launch(void* const* d_in, const int* in_sizes, int n_in,
                              void* d_out, int out_size, void* d_ws, size_t ws_size,
                              hipStream_t stream) {
    const float* X         = (const float*)d_in[0];
    const int*   cids      = (const int*)  d_in[1];
    const float* lm        = (const float*)d_in[2];
    const float* Wq        = (const float*)d_in[3];
    const float* Wk        = (const float*)d_in[4];
    const float* Wv        = (const float*)d_in[5];
    const float* centroids = (const float*)d_in[6];
    float* out = (float*)d_out;
    const int N = in_sizes[0] / 3;

    unsigned short* Wbuf = (unsigned short*)d_ws;   // [256][64] bf16 = 32 KB

    precompute_W<<<1, 256, 0, stream>>>(lm, Wq, Wk, centroids, Wbuf);
    const int blocks = (N + 255) / 256;
    fused_kernel<<<blocks, 256, 0, stream>>>(X, cids, Wbuf, Wv, out, N);
}

// Round 4
// 141.921 us; speedup vs baseline: 4.1595x; 1.3153x over previous
//
#include <hip/hip_runtime.h>
#include <math.h>

#define NUM_FREQS 10
#define EDIM 60            // 3 * 2 * NUM_FREQS
#define KPAD 64
#define TRADEOFF 1.0f
#define SCSTRIDE 276       // sC row stride (words): mult of 4 (b128 align), 69 = SCSTRIDE/4 coprime with 8 -> conflict-free spill

typedef __attribute__((ext_vector_type(8))) short bf16x8;
typedef __attribute__((ext_vector_type(4))) float f32x4;

__device__ __forceinline__ unsigned short f2bf(float f) {
    unsigned u = __builtin_bit_cast(unsigned, f);
    u += 0x7FFFu + ((u >> 16) & 1u);          // round-to-nearest-even
    return (unsigned short)(u >> 16);
}

// DPP butterfly helpers (VALU pipe, not DS): groups of 8 lanes.
// ctrl 0xB1 = quad_perm xor1, 0x4E = quad_perm xor2, 0x141 = row_half_mirror (xor7 within 8)
#define DPP_MOV(x, ctrl) __builtin_bit_cast(float, __builtin_amdgcn_update_dpp(0, __builtin_bit_cast(int, (x)), (ctrl), 0xF, 0xF, true))

__device__ __forceinline__ float bf8_sum(float x) {
    x += DPP_MOV(x, 0xB1);
    x += DPP_MOV(x, 0x4E);
    x += DPP_MOV(x, 0x141);
    return x;
}
__device__ __forceinline__ float bf8_max(float x) {
    x = fmaxf(x, DPP_MOV(x, 0xB1));
    x = fmaxf(x, DPP_MOV(x, 0x4E));
    x = fmaxf(x, DPP_MOV(x, 0x141));
    return x;
}

// NeRF posenc, layout enc[l*6 + s*3 + d] (s=0 sin, s=1 cos).
// One sincosf + 9 angle doublings per dim (freqs are exactly 2^l).
__device__ __forceinline__ void posenc3_fast(float x0, float x1, float x2, float* enc) {
    float xs[3] = {x0, x1, x2};
#pragma unroll
    for (int d = 0; d < 3; ++d) {
        float s, c;
        sincosf(xs[d], &s, &c);
        enc[0*6 + d] = s; enc[0*6 + 3 + d] = c;
#pragma unroll
        for (int l = 1; l < NUM_FREQS; ++l) {
            float s2 = 2.0f * s * c;
            float c2 = 1.0f - 2.0f * s * s;   // cos(2x)
            s = s2; c = c2;
            enc[l*6 + d] = s; enc[l*6 + 3 + d] = c;
        }
    }
}

// Stationary W [256 rows][64 K] bf16 in d_ws.
// Row r = 64*w + i:
//   i <  48: rgb row: cluster c = 16w + i/3, channel i%3  (lm row 48w + i)
//   i >= 48: score row of cluster c = 16w + (i-48):
//            Wscore_c[k] = sum_j Wq[j][k] * (posenc(centroid_c) . Wk[j]) / sqrt(5)
__global__ void precompute_W(const float* __restrict__ lm,
                             const float* __restrict__ Wq,
                             const float* __restrict__ Wk,
                             const float* __restrict__ centroids,
                             unsigned short* __restrict__ Wbuf) {
    if (blockIdx.x == 0) {
        // rgb rows: lm row rr -> Wbuf row 64*(rr/48) + rr%48, zero-padded K 60..63
        for (int idx = threadIdx.x; idx < 192 * 64; idx += 256) {
            const int rr = idx >> 6, k = idx & 63;
            const int w = rr / 48, i = rr - w * 48;
            const int r = 64 * w + i;
            const float v = (k < EDIM) ? lm[rr * EDIM + k] : 0.0f;
            Wbuf[r * 64 + k] = f2bf(v);
        }
    } else {
        const int c = threadIdx.x;
        if (c < 64) {
            float enc[EDIM];
            posenc3_fast(centroids[c*3+0], centroids[c*3+1], centroids[c*3+2], enc);
            const float inv_sqrt_dk = 0.4472135954999579f;
            float kq[5];
#pragma unroll
            for (int j = 0; j < 5; ++j) {
                float a = 0.0f;
                for (int k = 0; k < EDIM; ++k) a = fmaf(enc[k], Wk[j*EDIM + k], a);
                kq[j] = a * inv_sqrt_dk;
            }
            const int r = 64 * (c >> 4) + 48 + (c & 15);
            for (int k = 0; k < 64; ++k) {
                float a = 0.0f;
                if (k < EDIM) {
#pragma unroll
                    for (int j = 0; j < 5; ++j) a = fmaf(Wq[j*EDIM + k], kq[j], a);
                }
                Wbuf[r * 64 + k] = f2bf(a);
            }
        }
    }
}

// Fused kernel: 256 threads = 4 waves, 256 points per block.
// Wave w holds A-frags for W rows [64w, 64w+64) in registers.
// Loop sp=0..7: MFMA two 16-pt subtiles -> spill C^T [32 pts][276] via b128
// -> combine 32 points x 8 helpers (strided clusters, DPP reductions).
__global__ __launch_bounds__(256) void fused_kernel(
        const float* __restrict__ X,
        const int*   __restrict__ cluster_ids,
        const unsigned short* __restrict__ Wbuf,
        const float* __restrict__ Wv,
        float* __restrict__ out,
        int N) {
    __shared__ __align__(16) unsigned short sA[256 * KPAD];  // enc tile bf16, slot-swizzled (32 KB)
    __shared__ __align__(16) float sC[32 * SCSTRIDE];        // C^T tile (34.5 KB)

    const int tid  = threadIdx.x;
    const int lane = tid & 63;
    const int wv   = tid >> 6;
    const int g    = lane >> 4;
    const int l15  = lane & 15;

    // stationary A-fragments: A[m=l15][k = (kf*4+g)*8 + j] for rows 64wv + t*16 + l15
    bf16x8 afr[4][2];
    {
        const bf16x8* W8 = (const bf16x8*)Wbuf;
#pragma unroll
        for (int t = 0; t < 4; ++t)
#pragma unroll
            for (int kf = 0; kf < 2; ++kf)
                afr[t][kf] = W8[(wv*64 + t*16 + l15) * 8 + kf*4 + g];
    }

    // posenc: each thread encodes its own point into sA (16B-slot XOR swizzle)
    const int base = blockIdx.x * 256;
    {
        int n = base + tid; if (n >= N) n = N - 1;
        float enc[KPAD];
        posenc3_fast(X[n*3+0], X[n*3+1], X[n*3+2], enc);
        enc[60] = 0.f; enc[61] = 0.f; enc[62] = 0.f; enc[63] = 0.f;
#pragma unroll
        for (int u8 = 0; u8 < 8; ++u8) {
            const int slot = u8 ^ (tid & 7);
            bf16x8 v;
#pragma unroll
            for (int j = 0; j < 8; ++j) v[j] = (short)f2bf(enc[u8*8 + j]);
            *(bf16x8*)&sA[tid*KPAD + slot*8] = v;
        }
    }
    __syncthreads();

    const int p = tid >> 3;     // combine: point within 32-group
    const int h = tid & 7;      // helper 0..7 (8 consecutive lanes per point)

    float* o_out = out;
    float* o_km  = out + (size_t)N * 3;
    float* o_at  = out + (size_t)N * 6;

    for (int sp = 0; sp < 8; ++sp) {
        // --- MFMA for the two 16-pt subtiles of this group
        f32x4 acc[2][4];
#pragma unroll
        for (int u = 0; u < 2; ++u) {
            bf16x8 bfr[2];
            const int prow = (sp*2 + u)*16 + l15;
#pragma unroll
            for (int kf = 0; kf < 2; ++kf) {
                const int slot = (kf*4 + g) ^ (prow & 7);
                bfr[kf] = *(const bf16x8*)&sA[prow*KPAD + slot*8];
            }
#pragma unroll
            for (int t = 0; t < 4; ++t) {
                acc[u][t] = (f32x4){0.f, 0.f, 0.f, 0.f};
#pragma unroll
                for (int kf = 0; kf < 2; ++kf)
                    acc[u][t] = __builtin_amdgcn_mfma_f32_16x16x32_bf16(afr[t][kf], bfr[kf], acc[u][t], 0, 0, 0);
            }
        }

        __syncthreads();   // previous combine done reading sC

        // --- spill C^T: point row = u*16+l15, rows m = 64wv + 16t + 4g + rg (4 consecutive -> b128)
#pragma unroll
        for (int u = 0; u < 2; ++u)
#pragma unroll
            for (int t = 0; t < 4; ++t)
                *(f32x4*)&sC[(u*16 + l15) * SCSTRIDE + wv*64 + t*16 + g*4] = acc[u][t];

        __syncthreads();

        // --- combine: 32 points x 8 helpers; helper h covers clusters c = h + 8i
        {
            const int n  = base + sp*32 + p;
            const int nc = (n < N) ? n : (N - 1);
            const int cid = cluster_ids[nc];
            const float* col = &sC[p * SCSTRIDE];

            // scores: row m = 64*(c>>4) + 48 + (c&15);  c = h+8i -> 64*(i>>1) + 48 + 8*(i&1) + h
            float sc[8];
#pragma unroll
            for (int i = 0; i < 8; ++i)
                sc[i] = col[64*(i >> 1) + 48 + 8*(i & 1) + h];

            float m = fmaxf(fmaxf(fmaxf(sc[0], sc[1]), fmaxf(sc[2], sc[3])),
                            fmaxf(fmaxf(sc[4], sc[5]), fmaxf(sc[6], sc[7])));
            m = bf8_max(m);

            float e[8], S = 0.f;
#pragma unroll
            for (int i = 0; i < 8; ++i) { e[i] = __expf(sc[i] - m); S += e[i]; }

            // rgb rows: m = 64*(c>>4) + 3*(c&15) + ch = 64*(i>>1) + 24*(i&1) + 3h + ch
            float a0 = 0.f, a1 = 0.f, a2 = 0.f;
            float k0 = 0.f, k1 = 0.f, k2 = 0.f;
            const bool hm = (h == (cid & 7));
            const int  tg = cid >> 3;
#pragma unroll
            for (int i = 0; i < 8; ++i) {
                const int bo = 64*(i >> 1) + 24*(i & 1) + 3*h;
                const float r0 = col[bo], r1 = col[bo + 1], r2 = col[bo + 2];
                a0 = fmaf(e[i], r0, a0);
                a1 = fmaf(e[i], r1, a1);
                a2 = fmaf(e[i], r2, a2);
                const bool sel = hm && (tg == i);
                k0 = sel ? r0 : k0; k1 = sel ? r1 : k1; k2 = sel ? r2 : k2;
            }

            S  = bf8_sum(S);
            a0 = bf8_sum(a0); a1 = bf8_sum(a1); a2 = bf8_sum(a2);
            k0 = bf8_sum(k0); k1 = bf8_sum(k1); k2 = bf8_sum(k2);

            if (h == 0 && n < N) {
                const float inv = 1.0f / S;
                const float w0 = a0 * inv, w1 = a1 * inv, w2 = a2 * inv;
                // attention_rgb = Wv . (sum attn*rgb)
                const float at0 = Wv[0]*w0 + Wv[1]*w1 + Wv[2]*w2;
                const float at1 = Wv[3]*w0 + Wv[4]*w1 + Wv[5]*w2;
                const float at2 = Wv[6]*w0 + Wv[7]*w1 + Wv[8]*w2;
                const float oo0 = k0 * TRADEOFF + at0 * (1.0f - TRADEOFF);
                const float oo1 = k1 * TRADEOFF + at1 * (1.0f - TRADEOFF);
                const float oo2 = k2 * TRADEOFF + at2 * (1.0f - TRADEOFF);
                o_out[n*3+0] = oo0; o_out[n*3+1] = oo1; o_out[n*3+2] = oo2;
                o_km[n*3+0]  = k0;  o_km[n*3+1]  = k1;  o_km[n*3+2]  = k2;
                o_at[n*3+0]  = at0; o_at[n*3+1]  = at1; o_at[n*3+2]  = at2;
            }
        }
        __syncthreads();
    }
}

extern "C" void kernel_launch(void* const* d_in, const int* in_sizes, int n_in,
                              void* d_out, int out_size, void* d_ws, size_t ws_size,
                              hipStream_t stream) {
    const float* X         = (const float*)d_in[0];
    const int*   cids      = (const int*)  d_in[1];
    const float* lm        = (const float*)d_in[2];
    const float* Wq        = (const float*)d_in[3];
    const float* Wk        = (const float*)d_in[4];
    const float* Wv        = (const float*)d_in[5];
    const float* centroids = (const float*)d_in[6];
    float* out = (float*)d_out;
    const int N = in_sizes[0] / 3;

    unsigned short* Wbuf = (unsigned short*)d_ws;   // [256][64] bf16 = 32 KB

    precompute_W<<<2, 256, 0, stream>>>(lm, Wq, Wk, centroids, Wbuf);
    const int blocks = (N + 255) / 256;
    fused_kernel<<<blocks, 256, 0, stream>>>(X, cids, Wbuf, Wv, out, N);
}

// Round 5
// 132.987 us; speedup vs baseline: 4.4389x; 1.0672x over previous
//
#include <hip/hip_runtime.h>
#include <math.h>

#define NUM_FREQS 10
#define EDIM 60            // 3 * 2 * NUM_FREQS
#define KPAD 64
#define TRADEOFF 1.0f

typedef __attribute__((ext_vector_type(8))) short bf16x8;
typedef __attribute__((ext_vector_type(4))) float f32x4;

__device__ __forceinline__ unsigned short f2bf(float f) {
    unsigned u = __builtin_bit_cast(unsigned, f);
    u += 0x7FFFu + ((u >> 16) & 1u);          // round-to-nearest-even
    return (unsigned short)(u >> 16);
}

// xor16 lane exchange via ds_swizzle (BitMode: offset = (xor<<10)|(or<<5)|and)
__device__ __forceinline__ float swz16(float x) {
    return __builtin_bit_cast(float,
        __builtin_amdgcn_ds_swizzle(__builtin_bit_cast(int, x), 0x401F));
}

// NeRF posenc, layout enc[l*6 + s*3 + d] (s=0 sin, s=1 cos).
// One sincosf + 9 angle doublings per dim (freqs are exactly 2^l).
__device__ __forceinline__ void posenc3_fast(float x0, float x1, float x2, float* enc) {
    float xs[3] = {x0, x1, x2};
#pragma unroll
    for (int d = 0; d < 3; ++d) {
        float s, c;
        sincosf(xs[d], &s, &c);
        enc[0*6 + d] = s; enc[0*6 + 3 + d] = c;
#pragma unroll
        for (int l = 1; l < NUM_FREQS; ++l) {
            float s2 = 2.0f * s * c;
            float c2 = 1.0f - 2.0f * s * s;   // cos(2x)
            s = s2; c = c2;
            enc[l*6 + d] = s; enc[l*6 + 3 + d] = c;
        }
    }
}

// Single fused kernel: 256 threads = 4 waves, 256 points per block.
// Wave w owns clusters [16w, 16w+16). W-row map within wave (m-subtile t):
//   t = 0..2 : rgb channel t of cluster 16w + row  (lm row 3*(16w+row)+t)
//   t = 3    : attention-score row of cluster 16w + row (precomputed in-block)
// MFMA acc (lane g,l15): acc[t][rg] = value for cluster 16w+4g+rg, point l15.
// Softmax over 64 clusters: in-register per 8-cluster group (xor16 swizzle),
// 8 group-partials spilled to LDS, merged by a rotating 16-lane gather.
__global__ __launch_bounds__(256) void fused1(
        const float* __restrict__ X,
        const int*   __restrict__ cluster_ids,
        const float* __restrict__ lm,      // [192, 60]
        const float* __restrict__ Wq,      // [5, 60]
        const float* __restrict__ Wk,      // [5, 60]
        const float* __restrict__ Wv,      // [3, 3]
        const float* __restrict__ cents,   // [64, 3]
        float* __restrict__ out,
        int N) {
    __shared__ __align__(16) unsigned short sA[256 * KPAD];  // enc tile bf16, swizzled (32 KB)
    __shared__ __align__(16) float sParts[2][16][68];        // {m,S,a0,a1,a2} x 8 groups (8.5 KB)
    __shared__ __align__(16) float sKm[2][16][4];            // kmeans rgb per point (0.5 KB)
    __shared__ float sKq[64][5];                             // K-proj per cluster (1.3 KB)
    __shared__ int   sCid[256];                              // cluster ids (1 KB)

    const int tid  = threadIdx.x;
    const int lane = tid & 63;
    const int w    = tid >> 6;
    const int g    = lane >> 4;
    const int l15  = lane & 15;
    const int base = blockIdx.x * 256;

    // ---- own-point posenc -> sA (bf16, 16B-slot XOR swizzle), cid -> sCid
    {
        int n = base + tid; if (n >= N) n = N - 1;
        sCid[tid] = cluster_ids[n];
        float enc[KPAD];
        posenc3_fast(X[n*3+0], X[n*3+1], X[n*3+2], enc);
        enc[60] = 0.f; enc[61] = 0.f; enc[62] = 0.f; enc[63] = 0.f;
#pragma unroll
        for (int u8 = 0; u8 < 8; ++u8) {
            const int slot = u8 ^ (tid & 7);
            bf16x8 v;
#pragma unroll
            for (int j = 0; j < 8; ++j) v[j] = (short)f2bf(enc[u8*8 + j]);
            *(bf16x8*)&sA[tid*KPAD + slot*8] = v;
        }
    }

    // ---- kq partials: lane (g,l15) computes kq[c][g] for c = 16w+l15 (g==0 also j=4)
    {
        const int c = 16*w + l15;
        float enc[EDIM];
        posenc3_fast(cents[c*3+0], cents[c*3+1], cents[c*3+2], enc);
        const float isd = 0.4472135954999579f;  // 1/sqrt(5)
        const f32x4* wk4 = (const f32x4*)(Wk + g*EDIM);
        float a = 0.f;
#pragma unroll
        for (int q = 0; q < 15; ++q) {
            f32x4 v = wk4[q];
            a = fmaf(enc[q*4+0], v[0], a); a = fmaf(enc[q*4+1], v[1], a);
            a = fmaf(enc[q*4+2], v[2], a); a = fmaf(enc[q*4+3], v[3], a);
        }
        sKq[c][g] = a * isd;
        if (g == 0) {
            const f32x4* wk4b = (const f32x4*)(Wk + 4*EDIM);
            float b = 0.f;
#pragma unroll
            for (int q = 0; q < 15; ++q) {
                f32x4 v = wk4b[q];
                b = fmaf(enc[q*4+0], v[0], b); b = fmaf(enc[q*4+1], v[1], b);
                b = fmaf(enc[q*4+2], v[2], b); b = fmaf(enc[q*4+3], v[3], b);
            }
            sKq[c][4] = b * isd;
        }
    }

    // ---- rgb A-fragments straight from lm (global, L2-resident)
    bf16x8 afr[4][2];
#pragma unroll
    for (int t = 0; t < 3; ++t) {
        const float* rp = lm + (3*(16*w + l15) + t) * EDIM;
#pragma unroll
        for (int kf = 0; kf < 2; ++kf) {
            const int k0 = (kf*4 + g) * 8;
            float v[8];
            f32x4 p0 = *(const f32x4*)(rp + k0);
            v[0]=p0[0]; v[1]=p0[1]; v[2]=p0[2]; v[3]=p0[3];
            if (k0 + 4 < EDIM) {
                f32x4 p1 = *(const f32x4*)(rp + k0 + 4);
                v[4]=p1[0]; v[5]=p1[1]; v[6]=p1[2]; v[7]=p1[3];
            } else { v[4]=0.f; v[5]=0.f; v[6]=0.f; v[7]=0.f; }
            bf16x8 pk;
#pragma unroll
            for (int j = 0; j < 8; ++j) pk[j] = (short)f2bf(v[j]);
            afr[t][kf] = pk;
        }
    }

    // Wv into registers (needed by rotating gather)
    const float wv00 = Wv[0], wv01 = Wv[1], wv02 = Wv[2];
    const float wv10 = Wv[3], wv11 = Wv[4], wv12 = Wv[5];
    const float wv20 = Wv[6], wv21 = Wv[7], wv22 = Wv[8];

    __syncthreads();

    // ---- score A-fragments: W_c[k] = sum_j Wq[j][k] * kq[c][j]
    {
        const int c = 16*w + l15;
        const float kq0 = sKq[c][0], kq1 = sKq[c][1], kq2 = sKq[c][2],
                    kq3 = sKq[c][3], kq4 = sKq[c][4];
#pragma unroll
        for (int kf = 0; kf < 2; ++kf) {
            const int k0 = (kf*4 + g) * 8;
            bf16x8 pk;
#pragma unroll
            for (int j = 0; j < 8; ++j) {
                const int k = k0 + j;
                float a = 0.f;
                if (k < EDIM)
                    a = Wq[0*EDIM+k]*kq0 + Wq[1*EDIM+k]*kq1 + Wq[2*EDIM+k]*kq2
                      + Wq[3*EDIM+k]*kq3 + Wq[4*EDIM+k]*kq4;
                pk[j] = (short)f2bf(a);
            }
            afr[3][kf] = pk;
        }
    }

    float* o_out = out;
    float* o_km  = out + (size_t)N * 3;
    float* o_at  = out + (size_t)N * 6;

    for (int s = 0; s < 16; ++s) {
        // --- B-fragments for points s*16 .. s*16+15
        bf16x8 bfr[2];
        const int prow = s*16 + l15;
#pragma unroll
        for (int kf = 0; kf < 2; ++kf) {
            const int slot = (kf*4 + g) ^ (prow & 7);
            bfr[kf] = *(const bf16x8*)&sA[prow*KPAD + slot*8];
        }
        // --- MFMA: 4 m-subtiles (r,g,b,score) x K=64
        f32x4 acc[4];
#pragma unroll
        for (int t = 0; t < 4; ++t) {
            acc[t] = (f32x4){0.f, 0.f, 0.f, 0.f};
#pragma unroll
            for (int kf = 0; kf < 2; ++kf)
                acc[t] = __builtin_amdgcn_mfma_f32_16x16x32_bf16(afr[t][kf], bfr[kf], acc[t], 0, 0, 0);
        }

        // --- in-register combine (point = l15, clusters cbase..cbase+3)
        const int cid = sCid[s*16 + l15];
        const int cbase = 16*w + 4*g;

        const float sc0 = acc[3][0], sc1 = acc[3][1], sc2 = acc[3][2], sc3 = acc[3][3];
        const float m4 = fmaxf(fmaxf(sc0, sc1), fmaxf(sc2, sc3));
        const float m8 = fmaxf(m4, swz16(m4));   // max over 8-cluster group

        const float e0 = __expf(sc0 - m8), e1 = __expf(sc1 - m8),
                    e2 = __expf(sc2 - m8), e3 = __expf(sc3 - m8);
        const float S4 = e0 + e1 + e2 + e3;
        const float a04 = e0*acc[0][0] + e1*acc[0][1] + e2*acc[0][2] + e3*acc[0][3];
        const float a14 = e0*acc[1][0] + e1*acc[1][1] + e2*acc[1][2] + e3*acc[1][3];
        const float a24 = e0*acc[2][0] + e1*acc[2][1] + e2*acc[2][2] + e3*acc[2][3];

        const float S8 = S4  + swz16(S4);
        const float a0 = a04 + swz16(a04);
        const float a1 = a14 + swz16(a14);
        const float a2 = a24 + swz16(a24);

        // --- kmeans: unique owning lane writes directly
#pragma unroll
        for (int rg = 0; rg < 4; ++rg) {
            if (cbase + rg == cid) {
                *(f32x4*)&sKm[s & 1][l15][0] =
                    (f32x4){acc[0][rg], acc[1][rg], acc[2][rg], 0.f};
            }
        }

        // --- spill group partials (lanes g=0,2 hold the merged halves)
        if (!(g & 1)) {
            const int grp = w*2 + (g >> 1);
            float* pp = &sParts[s & 1][l15][grp*8];
            *(f32x4*)pp = (f32x4){m8, S8, a0, a1};
            pp[4] = a2;
        }

        // --- gather of previous subtile (rotating wave, overlaps this MFMA round)
        if (s > 0 && w == ((s - 1) & 3) && lane < 16) {
            const int sp = s - 1;
            const int n = base + sp*16 + lane;
            float mi[8], Si[8], A0[8], A1[8], A2[8];
            float mg = -INFINITY;
#pragma unroll
            for (int i = 0; i < 8; ++i) {
                const float* pp = &sParts[sp & 1][lane][i*8];
                f32x4 v = *(const f32x4*)pp;
                mi[i] = v[0]; Si[i] = v[1]; A0[i] = v[2]; A1[i] = v[3]; A2[i] = pp[4];
                mg = fmaxf(mg, mi[i]);
            }
            float S = 0.f, t0 = 0.f, t1 = 0.f, t2 = 0.f;
#pragma unroll
            for (int i = 0; i < 8; ++i) {
                const float f = __expf(mi[i] - mg);
                S  = fmaf(Si[i], f, S);
                t0 = fmaf(A0[i], f, t0); t1 = fmaf(A1[i], f, t1); t2 = fmaf(A2[i], f, t2);
            }
            const f32x4 km = *(const f32x4*)&sKm[sp & 1][lane][0];
            const float inv = 1.0f / S;
            const float u0 = t0*inv, u1 = t1*inv, u2 = t2*inv;
            const float at0 = wv00*u0 + wv01*u1 + wv02*u2;
            const float at1 = wv10*u0 + wv11*u1 + wv12*u2;
            const float at2 = wv20*u0 + wv21*u1 + wv22*u2;
            if (n < N) {
                const float oo0 = km[0]*TRADEOFF + at0*(1.0f - TRADEOFF);
                const float oo1 = km[1]*TRADEOFF + at1*(1.0f - TRADEOFF);
                const float oo2 = km[2]*TRADEOFF + at2*(1.0f - TRADEOFF);
                o_out[n*3+0] = oo0;   o_out[n*3+1] = oo1;   o_out[n*3+2] = oo2;
                o_km[n*3+0]  = km[0]; o_km[n*3+1]  = km[1]; o_km[n*3+2]  = km[2];
                o_at[n*3+0]  = at0;   o_at[n*3+1]  = at1;   o_at[n*3+2]  = at2;
            }
        }
        __syncthreads();
    }

    // --- final gather (subtile 15), wave 3
    if (w == 3 && lane < 16) {
        const int sp = 15;
        const int n = base + sp*16 + lane;
        float mi[8], Si[8], A0[8], A1[8], A2[8];
        float mg = -INFINITY;
#pragma unroll
        for (int i = 0; i < 8; ++i) {
            const float* pp = &sParts[sp & 1][lane][i*8];
            f32x4 v = *(const f32x4*)pp;
            mi[i] = v[0]; Si[i] = v[1]; A0[i] = v[2]; A1[i] = v[3]; A2[i] = pp[4];
            mg = fmaxf(mg, mi[i]);
        }
        float S = 0.f, t0 = 0.f, t1 = 0.f, t2 = 0.f;
#pragma unroll
        for (int i = 0; i < 8; ++i) {
            const float f = __expf(mi[i] - mg);
            S  = fmaf(Si[i], f, S);
            t0 = fmaf(A0[i], f, t0); t1 = fmaf(A1[i], f, t1); t2 = fmaf(A2[i], f, t2);
        }
        const f32x4 km = *(const f32x4*)&sKm[sp & 1][lane][0];
        const float inv = 1.0f / S;
        const float u0 = t0*inv, u1 = t1*inv, u2 = t2*inv;
        const float at0 = wv00*u0 + wv01*u1 + wv02*u2;
        const float at1 = wv10*u0 + wv11*u1 + wv12*u2;
        const float at2 = wv20*u0 + wv21*u1 + wv22*u2;
        if (n < N) {
            const float oo0 = km[0]*TRADEOFF + at0*(1.0f - TRADEOFF);
            const float oo1 = km[1]*TRADEOFF + at1*(1.0f - TRADEOFF);
            const float oo2 = km[2]*TRADEOFF + at2*(1.0f - TRADEOFF);
            o_out[n*3+0] = oo0;   o_out[n*3+1] = oo1;   o_out[n*3+2] = oo2;
            o_km[n*3+0]  = km[0]; o_km[n*3+1]  = km[1]; o_km[n*3+2]  = km[2];
            o_at[n*3+0]  = at0;   o_at[n*3+1]  = at1;   o_at[n*3+2]  = at2;
        }
    }
}

extern "C" void kernel_launch(void* const* d_in, const int* in_sizes, int n_in,
                              void* d_out, int out_size, void* d_ws, size_t ws_size,
                              hipStream_t stream) {
    const float* X         = (const float*)d_in[0];
    const int*   cids      = (const int*)  d_in[1];
    const float* lm        = (const float*)d_in[2];
    const float* Wq        = (const float*)d_in[3];
    const float* Wk        = (const float*)d_in[4];
    const float* Wv        = (const float*)d_in[5];
    const float* centroids = (const float*)d_in[6];
    float* out = (float*)d_out;
    const int N = in_sizes[0] / 3;

    const int blocks = (N + 255) / 256;
    fused1<<<blocks, 256, 0, stream>>>(X, cids, lm, Wq, Wk, Wv, centroids, out, N);
}

// Round 6
// 124.020 us; speedup vs baseline: 4.7598x; 1.0723x over previous
//
#include <hip/hip_runtime.h>
#include <math.h>

#define NUM_FREQS 10
#define EDIM 60            // 3 * 2 * NUM_FREQS
#define KPAD 64
#define TRADEOFF 1.0f

typedef __attribute__((ext_vector_type(8))) short bf16x8;
typedef __attribute__((ext_vector_type(4))) float f32x4;

// float -> bf16 (RNE) via clang native __bf16: lowers to v_cvt_pk_bf16_f32 on gfx950
__device__ __forceinline__ short bfc(float f) {
    return __builtin_bit_cast(short, (__bf16)f);
}

// xor16 lane exchange via ds_swizzle (BitMode: offset = (xor<<10)|(or<<5)|and)
__device__ __forceinline__ float swz16(float x) {
    return __builtin_bit_cast(float,
        __builtin_amdgcn_ds_swizzle(__builtin_bit_cast(int, x), 0x401F));
}

// NeRF posenc, layout enc[l*6 + s*3 + d] (s=0 sin, s=1 cos).
// Direct per-frequency hardware sin/cos in revolutions:
//   arg_l = x * 2^l / (2pi)  (exact float doubling), fract -> [0,1), v_sin/v_cos.
__device__ __forceinline__ void posenc3(float x0, float x1, float x2, float* enc) {
    const float inv2pi = 0.15915494309189535f;
    float xs[3] = {x0, x1, x2};
#pragma unroll
    for (int d = 0; d < 3; ++d) {
        float xr = xs[d] * inv2pi;
#pragma unroll
        for (int l = 0; l < NUM_FREQS; ++l) {
            const float fr = __builtin_amdgcn_fractf(xr);
            enc[l*6 + d]     = __builtin_amdgcn_sinf(fr);
            enc[l*6 + 3 + d] = __builtin_amdgcn_cosf(fr);
            xr *= 2.0f;   // exact
        }
    }
}

// Persistent fused kernel: 256 threads = 4 waves; grid-stride over 256-point chunks.
// Wave w owns clusters [16w, 16w+16). m-subtile t: t=0..2 rgb channel t, t=3 score.
// acc (lane g,l15): acc[t][rg] = value for cluster 16w+4g+rg, point l15.
// Softmax: in-register per 8-cluster group (xor16), 8 group-partials via LDS,
// merged by a rotating 16-lane gather wave.
__global__ __launch_bounds__(256) void fused2(
        const float* __restrict__ X,
        const int*   __restrict__ cluster_ids,
        const float* __restrict__ lm,      // [192, 60]
        const float* __restrict__ Wq,      // [5, 60]
        const float* __restrict__ Wk,      // [5, 60]
        const float* __restrict__ Wv,      // [3, 3]
        const float* __restrict__ cents,   // [64, 3]
        float* __restrict__ out,
        int N, int nChunks) {
    __shared__ __align__(16) unsigned short sA[256 * KPAD];  // enc tile bf16, swizzled (32 KB)
    __shared__ __align__(16) float sParts[2][16][68];        // {m,S,a0,a1,a2} x 8 groups
    __shared__ __align__(16) float sKm[2][16][4];            // kmeans rgb per point
    __shared__ float sKq[64][5];                             // K-proj per cluster
    __shared__ int   sCid[256];

    const int tid  = threadIdx.x;
    const int lane = tid & 63;
    const int w    = tid >> 6;
    const int g    = lane >> 4;
    const int l15  = lane & 15;

    // ================= per-block prologue (amortized over chunks) =================
    // kq partials: lane (g,l15) computes kq[c][g] for c = 16w+l15 (g==0 also j=4)
    {
        const int c = 16*w + l15;
        float enc[EDIM];
        posenc3(cents[c*3+0], cents[c*3+1], cents[c*3+2], enc);
        const float isd = 0.4472135954999579f;  // 1/sqrt(5)
        const f32x4* wk4 = (const f32x4*)(Wk + g*EDIM);
        float a = 0.f;
#pragma unroll
        for (int q = 0; q < 15; ++q) {
            f32x4 v = wk4[q];
            a = fmaf(enc[q*4+0], v[0], a); a = fmaf(enc[q*4+1], v[1], a);
            a = fmaf(enc[q*4+2], v[2], a); a = fmaf(enc[q*4+3], v[3], a);
        }
        sKq[c][g] = a * isd;
        if (g == 0) {
            const f32x4* wk4b = (const f32x4*)(Wk + 4*EDIM);
            float b = 0.f;
#pragma unroll
            for (int q = 0; q < 15; ++q) {
                f32x4 v = wk4b[q];
                b = fmaf(enc[q*4+0], v[0], b); b = fmaf(enc[q*4+1], v[1], b);
                b = fmaf(enc[q*4+2], v[2], b); b = fmaf(enc[q*4+3], v[3], b);
            }
            sKq[c][4] = b * isd;
        }
    }

    // rgb A-fragments straight from lm (L2-resident)
    bf16x8 afr[4][2];
#pragma unroll
    for (int t = 0; t < 3; ++t) {
        const float* rp = lm + (3*(16*w + l15) + t) * EDIM;
#pragma unroll
        for (int kf = 0; kf < 2; ++kf) {
            const int k0 = (kf*4 + g) * 8;
            float v[8];
            f32x4 p0 = *(const f32x4*)(rp + k0);
            v[0]=p0[0]; v[1]=p0[1]; v[2]=p0[2]; v[3]=p0[3];
            if (k0 + 4 < EDIM) {
                f32x4 p1 = *(const f32x4*)(rp + k0 + 4);
                v[4]=p1[0]; v[5]=p1[1]; v[6]=p1[2]; v[7]=p1[3];
            } else { v[4]=0.f; v[5]=0.f; v[6]=0.f; v[7]=0.f; }
            bf16x8 pk;
#pragma unroll
            for (int j = 0; j < 8; ++j) pk[j] = bfc(v[j]);
            afr[t][kf] = pk;
        }
    }

    const float wv00 = Wv[0], wv01 = Wv[1], wv02 = Wv[2];
    const float wv10 = Wv[3], wv11 = Wv[4], wv12 = Wv[5];
    const float wv20 = Wv[6], wv21 = Wv[7], wv22 = Wv[8];

    __syncthreads();

    // score A-fragments: W_c[k] = sum_j Wq[j][k] * kq[c][j], c = 16w+l15
    {
        const int c = 16*w + l15;
        const float kq0 = sKq[c][0], kq1 = sKq[c][1], kq2 = sKq[c][2],
                    kq3 = sKq[c][3], kq4 = sKq[c][4];
#pragma unroll
        for (int kf = 0; kf < 2; ++kf) {
            const int k0 = (kf*4 + g) * 8;
            bf16x8 pk;
#pragma unroll
            for (int j = 0; j < 8; ++j) {
                const int k = k0 + j;
                float a = 0.f;
                if (k < EDIM)
                    a = Wq[0*EDIM+k]*kq0 + Wq[1*EDIM+k]*kq1 + Wq[2*EDIM+k]*kq2
                      + Wq[3*EDIM+k]*kq3 + Wq[4*EDIM+k]*kq4;
                pk[j] = bfc(a);
            }
            afr[3][kf] = pk;
        }
    }

    float* o_out = out;
    float* o_km  = out + (size_t)N * 3;
    float* o_at  = out + (size_t)N * 6;

    // ================= chunk loop =================
    for (int chunk = blockIdx.x; chunk < nChunks; chunk += gridDim.x) {
        const int base = chunk << 8;

        __syncthreads();   // previous chunk fully done with sA/sParts/sKm

        // own-point posenc -> sA (bf16, 16B-slot XOR swizzle), cid -> sCid
        {
            int n = base + tid; if (n >= N) n = N - 1;
            sCid[tid] = cluster_ids[n];
            float enc[KPAD];
            posenc3(X[n*3+0], X[n*3+1], X[n*3+2], enc);
            enc[60] = 0.f; enc[61] = 0.f; enc[62] = 0.f; enc[63] = 0.f;
#pragma unroll
            for (int u8 = 0; u8 < 8; ++u8) {
                const int slot = u8 ^ (tid & 7);
                bf16x8 v;
#pragma unroll
                for (int j = 0; j < 8; ++j) v[j] = bfc(enc[u8*8 + j]);
                *(bf16x8*)&sA[tid*KPAD + slot*8] = v;
            }
        }
        __syncthreads();

        for (int s = 0; s < 16; ++s) {
            // B-fragments for points s*16 .. s*16+15
            bf16x8 bfr[2];
            const int prow = s*16 + l15;
#pragma unroll
            for (int kf = 0; kf < 2; ++kf) {
                const int slot = (kf*4 + g) ^ (prow & 7);
                bfr[kf] = *(const bf16x8*)&sA[prow*KPAD + slot*8];
            }
            // MFMA: 4 m-subtiles (r,g,b,score) x K=64
            f32x4 acc[4];
#pragma unroll
            for (int t = 0; t < 4; ++t) {
                acc[t] = (f32x4){0.f, 0.f, 0.f, 0.f};
#pragma unroll
                for (int kf = 0; kf < 2; ++kf)
                    acc[t] = __builtin_amdgcn_mfma_f32_16x16x32_bf16(afr[t][kf], bfr[kf], acc[t], 0, 0, 0);
            }

            // in-register combine (point = l15, clusters cbase..cbase+3)
            const int cid = sCid[s*16 + l15];
            const int cbase = 16*w + 4*g;

            const float sc0 = acc[3][0], sc1 = acc[3][1], sc2 = acc[3][2], sc3 = acc[3][3];
            const float m4 = fmaxf(fmaxf(sc0, sc1), fmaxf(sc2, sc3));
            const float m8 = fmaxf(m4, swz16(m4));

            const float e0 = __expf(sc0 - m8), e1 = __expf(sc1 - m8),
                        e2 = __expf(sc2 - m8), e3 = __expf(sc3 - m8);
            const float S4  = (e0 + e1) + (e2 + e3);
            const float a04 = fmaf(e0, acc[0][0], fmaf(e1, acc[0][1], fmaf(e2, acc[0][2], e3*acc[0][3])));
            const float a14 = fmaf(e0, acc[1][0], fmaf(e1, acc[1][1], fmaf(e2, acc[1][2], e3*acc[1][3])));
            const float a24 = fmaf(e0, acc[2][0], fmaf(e1, acc[2][1], fmaf(e2, acc[2][2], e3*acc[2][3])));

            const float S8 = S4  + swz16(S4);
            const float a0 = a04 + swz16(a04);
            const float a1 = a14 + swz16(a14);
            const float a2 = a24 + swz16(a24);

            // kmeans: unique owning lane writes directly
#pragma unroll
            for (int rg = 0; rg < 4; ++rg) {
                if (cbase + rg == cid) {
                    *(f32x4*)&sKm[s & 1][l15][0] =
                        (f32x4){acc[0][rg], acc[1][rg], acc[2][rg], 0.f};
                }
            }

            // spill group partials (lanes g=0,2 hold merged halves)
            if (!(g & 1)) {
                const int grp = w*2 + (g >> 1);
                float* pp = &sParts[s & 1][l15][grp*8];
                *(f32x4*)pp = (f32x4){m8, S8, a0, a1};
                pp[4] = a2;
            }

            // gather of previous subtile (rotating wave, overlaps MFMA round)
            if (s > 0 && w == ((s - 1) & 3) && lane < 16) {
                const int sp = s - 1;
                const int n = base + sp*16 + lane;
                float mi[8], Si[8], A0[8], A1[8], A2[8];
                float mg = -INFINITY;
#pragma unroll
                for (int i = 0; i < 8; ++i) {
                    const float* pp = &sParts[sp & 1][lane][i*8];
                    f32x4 v = *(const f32x4*)pp;
                    mi[i] = v[0]; Si[i] = v[1]; A0[i] = v[2]; A1[i] = v[3]; A2[i] = pp[4];
                    mg = fmaxf(mg, mi[i]);
                }
                float S = 0.f, t0 = 0.f, t1 = 0.f, t2 = 0.f;
#pragma unroll
                for (int i = 0; i < 8; ++i) {
                    const float f = __expf(mi[i] - mg);
                    S  = fmaf(Si[i], f, S);
                    t0 = fmaf(A0[i], f, t0); t1 = fmaf(A1[i], f, t1); t2 = fmaf(A2[i], f, t2);
                }
                const f32x4 km = *(const f32x4*)&sKm[sp & 1][lane][0];
                const float inv = 1.0f / S;
                const float u0 = t0*inv, u1 = t1*inv, u2 = t2*inv;
                const float at0 = wv00*u0 + wv01*u1 + wv02*u2;
                const float at1 = wv10*u0 + wv11*u1 + wv12*u2;
                const float at2 = wv20*u0 + wv21*u1 + wv22*u2;
                if (n < N) {
                    const float oo0 = km[0]*TRADEOFF + at0*(1.0f - TRADEOFF);
                    const float oo1 = km[1]*TRADEOFF + at1*(1.0f - TRADEOFF);
                    const float oo2 = km[2]*TRADEOFF + at2*(1.0f - TRADEOFF);
                    o_out[n*3+0] = oo0;   o_out[n*3+1] = oo1;   o_out[n*3+2] = oo2;
                    o_km[n*3+0]  = km[0]; o_km[n*3+1]  = km[1]; o_km[n*3+2]  = km[2];
                    o_at[n*3+0]  = at0;   o_at[n*3+1]  = at1;   o_at[n*3+2]  = at2;
                }
            }
            __syncthreads();
        }

        // final gather (subtile 15), wave 3; next chunk's top barrier protects buffers
        if (w == 3 && lane < 16) {
            const int sp = 15;
            const int n = base + sp*16 + lane;
            float mi[8], Si[8], A0[8], A1[8], A2[8];
            float mg = -INFINITY;
#pragma unroll
            for (int i = 0; i < 8; ++i) {
                const float* pp = &sParts[sp & 1][lane][i*8];
                f32x4 v = *(const f32x4*)pp;
                mi[i] = v[0]; Si[i] = v[1]; A0[i] = v[2]; A1[i] = v[3]; A2[i] = pp[4];
                mg = fmaxf(mg, mi[i]);
            }
            float S = 0.f, t0 = 0.f, t1 = 0.f, t2 = 0.f;
#pragma unroll
            for (int i = 0; i < 8; ++i) {
                const float f = __expf(mi[i] - mg);
                S  = fmaf(Si[i], f, S);
                t0 = fmaf(A0[i], f, t0); t1 = fmaf(A1[i], f, t1); t2 = fmaf(A2[i], f, t2);
            }
            const f32x4 km = *(const f32x4*)&sKm[sp & 1][lane][0];
            const float inv = 1.0f / S;
            const float u0 = t0*inv, u1 = t1*inv, u2 = t2*inv;
            const float at0 = wv00*u0 + wv01*u1 + wv02*u2;
            const float at1 = wv10*u0 + wv11*u1 + wv12*u2;
            const float at2 = wv20*u0 + wv21*u1 + wv22*u2;
            if (n < N) {
                const float oo0 = km[0]*TRADEOFF + at0*(1.0f - TRADEOFF);
                const float oo1 = km[1]*TRADEOFF + at1*(1.0f - TRADEOFF);
                const float oo2 = km[2]*TRADEOFF + at2*(1.0f - TRADEOFF);
                o_out[n*3+0] = oo0;   o_out[n*3+1] = oo1;   o_out[n*3+2] = oo2;
                o_km[n*3+0]  = km[0]; o_km[n*3+1]  = km[1]; o_km[n*3+2]  = km[2];
                o_at[n*3+0]  = at0;   o_at[n*3+1]  = at1;   o_at[n*3+2]  = at2;
            }
        }
    }
}

extern "C" void kernel_launch(void* const* d_in, const int* in_sizes, int n_in,
                              void* d_out, int out_size, void* d_ws, size_t ws_size,
                              hipStream_t stream) {
    const float* X         = (const float*)d_in[0];
    const int*   cids      = (const int*)  d_in[1];
    const float* lm        = (const float*)d_in[2];
    const float* Wq        = (const float*)d_in[3];
    const float* Wk        = (const float*)d_in[4];
    const float* Wv        = (const float*)d_in[5];
    const float* centroids = (const float*)d_in[6];
    float* out = (float*)d_out;
    const int N = in_sizes[0] / 3;

    const int nChunks = (N + 255) / 256;
    const int grid = nChunks < 768 ? nChunks : 768;   // 3 blocks/CU x 256 CU
    fused2<<<grid, 256, 0, stream>>>(X, cids, lm, Wq, Wk, Wv, centroids, out, N, nChunks);
}